// Round 13
// baseline (158.786 us; speedup 1.0000x reference)
//
#include <hip/hip_runtime.h>
#include <hip/hip_bf16.h>

// GraphSAGE fused kernels for MI355X (gfx950).
// N=768, NODE_IN=64, EDGE_IN=32, H=128, ROUNDS=2.
//
// Round 13: R12 streaming structure + per-chunk critical-path shaves:
// (1) spT[col][i] layout -> C-init = 2 contiguous f32x4 loads (was 8
// scattered dwords at 512B stride); (2) next-chunk spT+adj register
// prefetch (12 regs, issued under current MFMA burst); (3) be hoisted to
// 2 regs (was 2 LDS reads/chunk). k_prep/k_upd write spT transposed.

typedef __bf16 bf16x8 __attribute__((ext_vector_type(8)));
typedef float f32x4 __attribute__((ext_vector_type(4)));

#define NN 768

static __device__ __forceinline__ unsigned short to_bf16u(float x) {
    return __builtin_bit_cast(unsigned short, (__bf16)x);
}

// ---------------------------------------------------------------- fused prep
// blocks 0..2303   : ef[i][j][f] fp32 -> efT[j][i][f] bf16 (LDS-tiled)
// blocks 2304..2879: adj transpose (32x32 tiles)
// blocks 2880..2959: weight transposes We->WeT, Wa[H:]->Wa2T (bf16 k-minor)
// blocks 2960..3343: h0 = relu(nf@Wn+bn) and spT[k][i] = (h0@Wa[:H]+ba)[i][k]
__global__ __launch_bounds__(256) void k_prep(
                       const float* __restrict__ ef, unsigned short* __restrict__ efT,
                       const float* __restrict__ adj, float* __restrict__ adjT,
                       const float* __restrict__ We, const float* __restrict__ Wa,
                       unsigned short* __restrict__ WeT, unsigned short* __restrict__ Wa2T,
                       const float* __restrict__ nf, const float* __restrict__ Wn,
                       const float* __restrict__ bn, const float* __restrict__ ba,
                       float* __restrict__ h, float* __restrict__ spT) {
    const int b = blockIdx.x, tid = threadIdx.x;
    if (b < 2304) {
        __shared__ unsigned short tile[8 * 1288 + 8];  // plane 1288, row 40
        const int i0 = (b % 24) * 32, j0 = (b / 24) * 8;
        {
            const int jj = tid >> 5, ff = tid & 31;
#pragma unroll 4
            for (int i = 0; i < 32; ++i) {
                float v = ef[((size_t)(i0 + i) * NN + j0 + jj) * 32 + ff];
                tile[jj * 1288 + i * 40 + ff] = to_bf16u(v);
            }
        }
        __syncthreads();
        const int tp = tid & 31, j = tid >> 5;
        unsigned short* dst = efT + ((size_t)(j0 + j) * NN + i0) * 32;
#pragma unroll
        for (int v = 0; v < 4; ++v) {
            int flat = v * 256 + tp * 8;
            int i = flat >> 5, f = flat & 31;
            bf16x8 val = *reinterpret_cast<const bf16x8*>(&tile[j * 1288 + i * 40 + f]);
            *reinterpret_cast<bf16x8*>(dst + flat) = val;
        }
    } else if (b < 2880) {
        __shared__ float tile[32][33];
        int bb = b - 2304;
        int bx = bb % 24, by = bb / 24;
        int tx = tid & 31, ty = tid >> 5;  // 32 x 8
#pragma unroll
        for (int yy = 0; yy < 32; yy += 8)
            tile[ty + yy][tx] = adj[(size_t)(by * 32 + ty + yy) * NN + bx * 32 + tx];
        __syncthreads();
#pragma unroll
        for (int yy = 0; yy < 32; yy += 8)
            adjT[(size_t)(bx * 32 + ty + yy) * NN + by * 32 + tx] = tile[tx][ty + yy];
    } else if (b < 2960) {
        int g = (b - 2880) * 256 + tid;
        if (g < 128 * 32) {
            int c = g >> 5, f = g & 31;
            WeT[g] = to_bf16u(We[f * 128 + c]);
        } else {
            int g2 = g - 128 * 32;
            int c = g2 >> 7, k = g2 & 127;
            Wa2T[g2] = to_bf16u(Wa[(128 + k) * 128 + c]);
        }
    } else {
        __shared__ float nf_l[2][64];
        __shared__ float h_l[2][128];
        int row = tid >> 7, t = tid & 127;
        int i = (b - 2960) * 2 + row;
        if (t < 64) nf_l[row][t] = nf[i * 64 + t];
        __syncthreads();
        float acc = bn[t];
#pragma unroll 8
        for (int f = 0; f < 64; ++f) acc += nf_l[row][f] * Wn[f * 128 + t];
        acc = fmaxf(acc, 0.f);
        h[i * 128 + t] = acc;
        h_l[row][t] = acc;
        __syncthreads();
        float spv = ba[t];
#pragma unroll 8
        for (int f = 0; f < 128; ++f) spv += h_l[row][f] * Wa[f * 128 + t];
        spT[(size_t)t * NN + i] = spv;
    }
}

// ---------------------------------------------------------------- streaming k_big
// Block = receiver j. 8 waves in 2x4 (wr x wc). Chunk = 32 sequential
// senders, 24 chunks. adj applied as av multiply post-relu.
__global__ __launch_bounds__(512) void k_big_s(
    const unsigned short* __restrict__ efT, const float* __restrict__ adjT,
    const float* __restrict__ spT, const unsigned short* __restrict__ WeT,
    const unsigned short* __restrict__ Wa2T, const float* __restrict__ be,
    float* __restrict__ agg) {
    __shared__ __align__(16) unsigned short e_lds[2][2][16 * 128];
    __shared__ float adj_lds[NN];
    __shared__ float wred[8];
    __shared__ float s_invdeg;

    const int tid  = threadIdx.x;
    const int j    = blockIdx.x;
    const int lane = tid & 63;
    const int wv   = tid >> 6;
    const int wr   = wv >> 2;
    const int wc   = wv & 3;
    const int lg   = lane >> 4;
    const int lr   = lane & 15;

    // stage adj column j (coalesced) + degree
    float asum = 0.f;
    for (int k = tid; k < NN; k += 512) {
        float a = adjT[(size_t)j * NN + k];
        adj_lds[k] = a;
        asum += a;
    }
#pragma unroll
    for (int off = 32; off; off >>= 1) asum += __shfl_down(asum, off);
    if (lane == 0) wred[wv] = asum;

    bf16x8 bwe[2];
    bf16x8 bwa[2][4];
    float bereg[2];
#pragma unroll
    for (int t = 0; t < 2; ++t) {
        const int col = 32 * wc + 16 * t + lr;
        bwe[t] = *reinterpret_cast<const bf16x8*>(WeT + col * 32 + 8 * lg);
        bereg[t] = be[col];
#pragma unroll
        for (int s = 0; s < 4; ++s)
            bwa[t][s] = *reinterpret_cast<const bf16x8*>(Wa2T + col * 128 + 32 * s + 8 * lg);
    }
    __syncthreads();
    if (tid == 0) {
        float d = 0.f;
#pragma unroll
        for (int w = 0; w < 8; ++w) d += wred[w];
        s_invdeg = 1.0f / fmaxf(d, 1.0f);
    }

    float aggp[2] = {0.f, 0.f};

    // sequential streaming load: wave covers 16 consecutive rows = 1KB run
    auto load_ef = [&](int n, bf16x8& x) {
        int row = 32 * n + 16 * wr + lr;
        x = *reinterpret_cast<const bf16x8*>(efT + ((size_t)j * NN + row) * 32 + 8 * lg);
    };
    // C-init + mask for chunk n: 2 contiguous f32x4 from spT + 1 from adj_lds
    auto load_sp = [&](int n, f32x4* spv, f32x4& av) {
        const int i0 = 32 * n + 16 * wr + 4 * lg;
#pragma unroll
        for (int t = 0; t < 2; ++t)
            spv[t] = *reinterpret_cast<const f32x4*>(spT + (size_t)(32 * wc + 16 * t + lr) * NN + i0);
        av = *reinterpret_cast<const f32x4*>(&adj_lds[i0]);
    };
    auto gemm1 = [&](bf16x8 a, int buf) {
#pragma unroll
        for (int t = 0; t < 2; ++t) {
            const int col = 32 * wc + 16 * t + lr;
            f32x4 c;
            c[0] = bereg[t]; c[1] = bereg[t]; c[2] = bereg[t]; c[3] = bereg[t];
            f32x4 C1 = __builtin_amdgcn_mfma_f32_16x16x32_bf16(a, bwe[t], c, 0, 0, 0);
#pragma unroll
            for (int r = 0; r < 4; ++r) {
                int row = 4 * lg + r;
                int idx = (row * 128 + col) ^ ((row & 7) << 3);
                e_lds[buf][wr][idx] = to_bf16u(fmaxf(C1[r], 0.f));
            }
        }
    };

    bf16x8 cA;
    f32x4 spv_c[2], av_c;
    load_ef(0, cA);
    load_sp(0, spv_c, av_c);
    gemm1(cA, 0);
    load_ef(1, cA);
    __syncthreads();   // E[0] ready

    for (int n = 0; n < 24; ++n) {
        const int b = n & 1;
        bf16x8 pA;
        if (n + 2 < 24) load_ef(n + 2, pA);
        if (n + 1 < 24) gemm1(cA, b ^ 1);

        bf16x8 ae[4];
#pragma unroll
        for (int s = 0; s < 4; ++s) {
            int idx = (lr * 128 + 32 * s + 8 * lg) ^ ((lr & 7) << 3);
            ae[s] = *reinterpret_cast<const bf16x8*>(&e_lds[b][wr][idx]);
        }
        // issue next chunk's C-init/mask loads under this chunk's MFMA burst
        f32x4 spv_n[2], av_n;
        if (n + 1 < 24) load_sp(n + 1, spv_n, av_n);

#pragma unroll
        for (int t = 0; t < 2; ++t) {
            f32x4 acc = spv_c[t];
#pragma unroll
            for (int s = 0; s < 4; ++s)
                acc = __builtin_amdgcn_mfma_f32_16x16x32_bf16(ae[s], bwa[t][s], acc, 0, 0, 0);
#pragma unroll
            for (int r = 0; r < 4; ++r)
                aggp[t] += fmaxf(acc[r], 0.f) * av_c[r];
        }

        if (n + 1 < 24) {
            spv_c[0] = spv_n[0]; spv_c[1] = spv_n[1]; av_c = av_n;
        }
        if (n + 2 < 24) cA = pA;
        __syncthreads();
    }

    float* red = reinterpret_cast<float*>(&e_lds[0][0][0]);  // [8][32]
#pragma unroll
    for (int t = 0; t < 2; ++t) {
        float v = aggp[t];
        v += __shfl_xor(v, 16);
        v += __shfl_xor(v, 32);
        if (lane < 16) red[wv * 32 + 16 * t + lane] = v;
    }
    __syncthreads();
    if (tid < 128) {
        int wcol = tid >> 5, c32 = tid & 31;
        agg[(size_t)j * 128 + tid] =
            (red[wcol * 32 + c32] + red[(4 + wcol) * 32 + c32]) * s_invdeg;
    }
}

// ---------------------------------------------------------------- update (+ next-round spT, or final out)
template <int LAST>
__global__ __launch_bounds__(256) void k_upd(
                      const float* __restrict__ h_in, const float* __restrict__ agg,
                      const float* __restrict__ Wu, const float* __restrict__ bu,
                      const float* __restrict__ Wa, const float* __restrict__ ba,
                      float* __restrict__ h_out, float* __restrict__ spT,
                      float* __restrict__ out) {
    __shared__ float buf[2][256];
    __shared__ float hn[2][128];
    const int tid = threadIdx.x;
    const int row = tid >> 7, t = tid & 127;
    const int i = blockIdx.x * 2 + row;
    buf[row][t] = h_in[i * 128 + t];
    buf[row][128 + t] = agg[i * 128 + t];
    __syncthreads();
    float acc = bu[t];
#pragma unroll 8
    for (int f = 0; f < 256; ++f) acc += buf[row][f] * Wu[f * 128 + t];
    acc = fmaxf(acc, 0.f);
    if (LAST) {
        out[i * 128 + t] = acc;
    } else {
        h_out[i * 128 + t] = acc;
        hn[row][t] = acc;
        __syncthreads();
        float spv = ba[t];
#pragma unroll 8
        for (int f = 0; f < 128; ++f) spv += hn[row][f] * Wa[f * 128 + t];
        spT[(size_t)t * NN + i] = spv;
    }
}

// ---------------------------------------------------------------- graph embedding
__global__ __launch_bounds__(64) void k_gemb(const float* __restrict__ out_h, float* __restrict__ out) {
    int c = blockIdx.x, l = threadIdx.x;
    float acc = 0.f;
    for (int i = l; i < NN; i += 64) acc += out_h[(size_t)i * 128 + c];
#pragma unroll
    for (int off = 32; off; off >>= 1) acc += __shfl_down(acc, off);
    if (l == 0) out[NN * 128 + c] = acc * (1.0f / 768.0f);
}

extern "C" void kernel_launch(void* const* d_in, const int* in_sizes, int n_in,
                              void* d_out, int out_size, void* d_ws, size_t ws_size,
                              hipStream_t stream) {
    const float* nf  = (const float*)d_in[0];
    const float* ef  = (const float*)d_in[1];
    const float* adj = (const float*)d_in[2];
    const float* Wn  = (const float*)d_in[3];
    const float* bn  = (const float*)d_in[4];
    const float* We  = (const float*)d_in[5];
    const float* be  = (const float*)d_in[6];
    const float* Wa  = (const float*)d_in[7];
    const float* ba  = (const float*)d_in[8];
    const float* Wu  = (const float*)d_in[9];
    const float* bu  = (const float*)d_in[10];
    float* out = (float*)d_out;

    // workspace: h | agg | spT | adjT | WeT | Wa2T | efT(bf16)  (~41.3 MB; ws ~302MB)
    float* h_buf = (float*)d_ws;
    float* agg   = h_buf + NN * 128;
    float* spT   = agg + NN * 128;
    float* adjT  = spT + 128 * NN;
    unsigned short* WeT  = (unsigned short*)(adjT + NN * NN);
    unsigned short* Wa2T = WeT + 128 * 32;
    unsigned short* efT  = Wa2T + 128 * 128;

    k_prep<<<3344, 256, 0, stream>>>(ef, efT, adj, adjT, We, Wa, WeT, Wa2T,
                                     nf, Wn, bn, ba, h_buf, spT);

    k_big_s<<<NN, 512, 0, stream>>>(efT, adjT, spT, WeT, Wa2T, be, agg);
    k_upd<0><<<NN / 2, 256, 0, stream>>>(h_buf, agg, Wu, bu, Wa, ba, h_buf, spT, out);
    k_big_s<<<NN, 512, 0, stream>>>(efT, adjT, spT, WeT, Wa2T, be, agg);
    k_upd<1><<<NN / 2, 256, 0, stream>>>(h_buf, agg, Wu, bu, Wa, ba, h_buf, spT, out);

    k_gemb<<<128, 64, 0, stream>>>(out, out);
}